// Round 4
// baseline (540.296 us; speedup 1.0000x reference)
//
#include <hip/hip_runtime.h>
#include <hip/hip_bf16.h>

#define BB 8
#define CC 256
#define HH 128
#define WW 128

typedef __attribute__((ext_vector_type(8))) short bf16x8;
typedef __attribute__((ext_vector_type(4))) float f32x4;

// fp32 -> bf16 round-to-nearest-even
static __device__ __forceinline__ unsigned short f2bf(float f) {
  unsigned int u = __builtin_bit_cast(unsigned int, f);
  u += 0x7fffu + ((u >> 16) & 1u);
  return (unsigned short)(u >> 16);
}

// async 16B global->LDS; LDS dest = wave-uniform base + lane*16
static __device__ __forceinline__ void async16(const void* g, void* l) {
#if __has_builtin(__builtin_amdgcn_global_load_lds)
  __builtin_amdgcn_global_load_lds(
      (__attribute__((address_space(1))) void*)(unsigned long long)(g),
      (__attribute__((address_space(3))) void*)(unsigned int)(unsigned long long)(l),
      16, 0, 0);
#else
  *(bf16x8*)l = *(const bf16x8*)g;
#endif
}

// ---------------------------------------------------------------------------
// Kernel 1: w_deform [co][ci][3][3] fp32 -> Wt2 [tap][ci_octet][co][8] bf16.
// LDS-tiled: 32 blocks x 8 co each; loads AND stores fully coalesced (the
// round-1..3 version had lanes striding 36 B -> ~9x fetch amplification).
// Also zeroes sums[] (folds the hipMemsetAsync graph node).
// ---------------------------------------------------------------------------
__global__ __launch_bounds__(256) void k_convert_w(const float* __restrict__ w,
                                                   unsigned short* __restrict__ Wt,
                                                   float* __restrict__ sums) {
  __shared__ unsigned short lw[8 * 2304];  // [cl][ci][tap] bf16, 36.9 KB
  const int t = threadIdx.x;
  const int co0 = blockIdx.x << 3;
  // zero sums: 10240 floats across 32 blocks x 256 threads x 2
  {
    const int z = (blockIdx.x * 256 + t) * 2;
    if (z < 10240) {
      sums[z] = 0.f;
      if (z + 1 < 10240) sums[z + 1] = 0.f;
    }
  }
  const float* src = w + co0 * 2304;
  for (int k = t; k < 18432; k += 256) lw[k] = f2bf(src[k]);  // coalesced
  __syncthreads();
  for (int g = t; g < 18432; g += 256) {
    const int tap = g >> 11, rem = g & 2047;
    const int o = rem >> 6, rem2 = rem & 63;
    const int cl = rem2 >> 3, e = rem2 & 7;
    // dest ((tap*32+o)*256 + co0+cl)*8 + e : consecutive g -> consecutive dest
    Wt[(((tap << 5) + o) << 11) + ((co0 + cl) << 3) + e] =
        lw[cl * 2304 + ((o << 3) + e) * 9 + tap];
  }
}

// ---------------------------------------------------------------------------
// Kernel 2: x [b][c][h][w] fp32 -> Xc2 [b][h][ci_octet][w][8] bf16,
// fused: per-(b,ci) total sum S, edge row sums R0/R1, edge col sums C0/C1.
// sums layout: S|R0|R1|C0|C1, each 2048 f32.
// ---------------------------------------------------------------------------
__global__ __launch_bounds__(256) void k_transpose_x(const float* __restrict__ x,
                                                     unsigned short* __restrict__ Xc,
                                                     float* __restrict__ sums) {
  __shared__ float tile[64][65];
  const int t = threadIdx.x;
  const int bz = blockIdx.z;
  const int b = bz >> 7, h = bz & 127;
  const int c0 = blockIdx.y << 6, w0 = blockIdx.x << 6;
  const float* xp = x + (((b * CC) * HH) + h) * WW;
#pragma unroll
  for (int i = 0; i < 4; ++i) {
    int idx = t + (i << 8);
    int cr = idx >> 4, wq = idx & 15;
    float4 v = *(const float4*)(xp + (c0 + cr) * (HH * WW) + w0 + (wq << 2));
    tile[cr][(wq << 2) + 0] = v.x;
    tile[cr][(wq << 2) + 1] = v.y;
    tile[cr][(wq << 2) + 2] = v.z;
    tile[cr][(wq << 2) + 3] = v.w;
  }
  __syncthreads();
  // ---- write out in [octet][w][8] layout ----
  const int ob = c0 >> 3;
#pragma unroll
  for (int i = 0; i < 2; ++i) {
    int g = t + (i << 8);          // 0..511
    int o = g >> 6, wr = g & 63;
    bf16x8 v;
#pragma unroll
    for (int e = 0; e < 8; ++e) v[e] = (short)f2bf(tile[(o << 3) + e][wr]);
    *(bf16x8*)(Xc + ((((b << 7) + h) * 32) + ob + o) * 1024 + (w0 + wr) * 8) = v;
  }
  // ---- fused partial sums ----
  {
    const int c = t >> 2, seg = t & 3;
    float s = 0.f;
#pragma unroll
    for (int k = 0; k < 16; ++k) s += tile[c][(seg << 4) + k];
    s += __shfl_xor(s, 1);
    s += __shfl_xor(s, 2);
    const int ci = b * CC + c0 + c;
    if (seg == 0) {
      atomicAdd(&sums[ci], s);                       // S
      if (h == 0)   atomicAdd(&sums[2048 + ci], s);  // R0
      if (h == 127) atomicAdd(&sums[4096 + ci], s);  // R1
      if (w0 == 0)  atomicAdd(&sums[6144 + ci], tile[c][0]);    // C0 (w=0)
    }
    if (seg == 3 && w0 == 64) atomicAdd(&sums[8192 + ci], tile[c][63]);  // C1 (w=127)
  }
}

// ---------------------------------------------------------------------------
// Kernel 3: closed-form pool + SE head. One block per batch.
// tapsum(kh,kw) = S - excluded_row - excluded_col + corner.
// Phases 2/3 lane-split-K with coalesced float4 reads + shuffle reduce.
// ---------------------------------------------------------------------------
__global__ __launch_bounds__(256) void k_pool_se(
    const float* __restrict__ x, const float* __restrict__ w,
    const float* __restrict__ bd, const float* __restrict__ w1,
    const float* __restrict__ b1, const float* __restrict__ w2,
    const float* __restrict__ b2, const float* __restrict__ sums,
    float* __restrict__ scale) {
  __shared__ float ts[2304];   // flat [ci*9 + tap]
  __shared__ float p[CC];
  __shared__ float h1[64];
  const int b = blockIdx.x, t = threadIdx.x;
  const int lane = t & 63, wid = t >> 6;
  // phase 1: t = ci
  {
    const int ci = b * CC + t;
    const float S  = sums[ci];
    const float R0 = sums[2048 + ci], R1 = sums[4096 + ci];
    const float C0 = sums[6144 + ci], C1 = sums[8192 + ci];
    const float* xp = x + ci * (HH * WW);
    const float x00 = xp[0], x0W = xp[127];
    const float xH0 = xp[127 * 128], xHW = xp[127 * 128 + 127];
    const float er[3] = {R1, 0.f, R0};
    const float ec[3] = {C1, 0.f, C0};
#pragma unroll
    for (int kh = 0; kh < 3; ++kh)
#pragma unroll
      for (int kw = 0; kw < 3; ++kw) {
        float corner = 0.f;
        if (kh == 0 && kw == 0) corner = xHW;
        if (kh == 0 && kw == 2) corner = xH0;
        if (kh == 2 && kw == 0) corner = x0W;
        if (kh == 2 && kw == 2) corner = x00;
        ts[t * 9 + kh * 3 + kw] = S - er[kh] - ec[kw] + corner;
      }
  }
  __syncthreads();
  // phase 2: each wave handles 64 co; lanes split K=2304 (coalesced)
  {
    float4 tv[9];
#pragma unroll
    for (int q = 0; q < 9; ++q) tv[q] = *(const float4*)&ts[(q * 64 + lane) * 4];
    for (int i = 0; i < 64; ++i) {
      const int co = (wid << 6) + i;
      const float4* wr = (const float4*)(w + co * 2304) + lane;
      float s = 0.f;
#pragma unroll
      for (int q = 0; q < 9; ++q) {
        float4 wv = wr[q * 64];
        s += wv.x * tv[q].x + wv.y * tv[q].y + wv.z * tv[q].z + wv.w * tv[q].w;
      }
      s += __shfl_xor(s, 1);  s += __shfl_xor(s, 2);  s += __shfl_xor(s, 4);
      s += __shfl_xor(s, 8);  s += __shfl_xor(s, 16); s += __shfl_xor(s, 32);
      if (lane == 0) p[co] = bd[co] + s * (1.0f / 16384.0f);
    }
  }
  __syncthreads();
  // phase 3: wave 0, lanes split K=256 (coalesced)
  if (wid == 0) {
    const float4 pv = *(const float4*)&p[lane * 4];
    for (int r = 0; r < 64; ++r) {
      float4 wv = ((const float4*)(w1 + r * CC))[lane];
      float s = wv.x * pv.x + wv.y * pv.y + wv.z * pv.z + wv.w * pv.w;
      s += __shfl_xor(s, 1);  s += __shfl_xor(s, 2);  s += __shfl_xor(s, 4);
      s += __shfl_xor(s, 8);  s += __shfl_xor(s, 16); s += __shfl_xor(s, 32);
      if (lane == 0) {
        float v = b1[r] + s;
        h1[r] = v > 0.f ? v : 0.f;
      }
    }
  }
  __syncthreads();
  // phase 4: t = co
  {
    float s = b2[t];
    const float* wr = w2 + t * 64;
#pragma unroll
    for (int k = 0; k < 64; ++k) s += wr[k] * h1[k];
    scale[b * CC + t] = 1.0f / (1.0f + expf(-s));
  }
}

// ---------------------------------------------------------------------------
// Kernel 4: implicit-GEMM conv, MFMA bf16. Block = 128 co x one W row.
// A from L2 (Wt2 1.2 MB), B double-buffered in LDS via global_load_lds, one
// barrier per ci-chunk. Epilogue fuses +bias, *scale. Launched as TWO
// half-grids (yoff) this round so rocprof top-5 can surface other kernels.
// ---------------------------------------------------------------------------
__global__ __launch_bounds__(256, 3) void k_conv(
    const unsigned short* __restrict__ Xc, const unsigned short* __restrict__ Wt,
    const float* __restrict__ bias, const float* __restrict__ scale,
    float* __restrict__ out, int yoff) {
  __shared__ __align__(16) unsigned short Xs[2 * 12480];  // [buf][dh:3][oct:4][wp:130][8]
  const int t = threadIdx.x;
  const int lin = ((blockIdx.y + yoff) << 1) | blockIdx.x;
  const int Wk = ((lin & 7) << 8) | (lin >> 3);   // XCD k -> b=k, contiguous h
  const int m0 = (Wk & 1) << 7;
  const int bh = Wk >> 1;
  const int b = bh >> 7, h = bh & 127;
  const int lane = t & 63, wid = t >> 6;
  const int wave_m = (wid & 1) << 6, wave_n = (wid >> 1) << 6;
  const int n0 = lane & 15, quad = lane >> 4;
  const int part = wid & 1, rsel = wid >> 1;

  bf16x8 z8 = {0, 0, 0, 0, 0, 0, 0, 0};
  // zero halo columns wp=0 and wp=129 (both buffers), once
  if (t < 48) {
    int bi = t / 24, rem = t % 24;
    int dh = rem >> 3, rem2 = rem & 7, q = rem2 >> 1, side = rem2 & 1;
    *(bf16x8*)&Xs[bi * 12480 + dh * 4160 + q * 1040 + (side ? 1032 : 0)] = z8;
  }
  // out-of-image rows stay zero (staging skips them)
  if (h == 0 || h == 127) {
    const int dhz = (h == 0) ? 0 : 2;
    for (int g = t; g < 1040; g += 256) {
      int bi = g >= 520, gg = g - bi * 520;
      *(bf16x8*)&Xs[bi * 12480 + dhz * 4160 + gg * 8] = z8;
    }
  }

  auto stage = [&](int cb8, int bi) {
    const int ob = cb8 << 2;
#pragma unroll
    for (int r = 0; r < 6; ++r) {
      const int rr = (r << 1) | rsel;      // 12 regions of 2 KB: (dh, octet)
      const int dh = rr >> 2, q = rr & 3;
      const int hh = h - 1 + dh;
      if (hh >= 0 && hh < HH) {
        const unsigned short* gp =
            Xc + ((((b << 7) + hh) * 32 + ob + q) << 10) + (part << 9) + (lane << 3);
        unsigned short* lp =
            &Xs[bi * 12480 + dh * 4160 + q * 1040 + 8 + (part << 9) + (lane << 3)];
        async16(gp, lp);
      }
    }
  };

  f32x4 acc[4][4];
  f32x4 zero4 = {0.f, 0.f, 0.f, 0.f};
#pragma unroll
  for (int i = 0; i < 4; ++i)
#pragma unroll
    for (int j = 0; j < 4; ++j) acc[i][j] = zero4;

  stage(0, 0);
  __syncthreads();

  for (int cb8 = 0; cb8 < 8; ++cb8) {
    const int cur = cb8 & 1;
    if (cb8 < 7) stage(cb8 + 1, cur ^ 1);
    // A base: Wt2[tap][(cb8*4)+quad][co][8]; B base in current Xs buffer
    const unsigned short* wb =
        Wt + ((((cb8 << 2) + quad) << 8) + m0 + wave_m + n0) * 8;
    const unsigned short* xb = &Xs[cur * 12480 + quad * 1040 + (wave_n + n0) * 8];

    bf16x8 af[3][4], bg[2][4];
#pragma unroll
    for (int i = 0; i < 4; ++i) af[0][i] = *(const bf16x8*)(wb + i * 128);
#pragma unroll
    for (int i = 0; i < 4; ++i) af[1][i] = *(const bf16x8*)(wb + 65536 + i * 128);
#pragma unroll
    for (int j = 0; j < 4; ++j) bg[0][j] = *(const bf16x8*)(xb + (j << 4) * 8);

#pragma unroll
    for (int tap = 0; tap < 9; ++tap) {
      if (tap < 7) {   // A prefetch, 2 taps ahead
#pragma unroll
        for (int i = 0; i < 4; ++i)
          af[(tap + 2) % 3][i] = *(const bf16x8*)(wb + (tap + 2) * 65536 + i * 128);
      }
      if (tap < 8) {   // B prefetch, 1 tap ahead
        const int kh1 = (tap + 1) / 3, kw1 = (tap + 1) % 3;
#pragma unroll
        for (int j = 0; j < 4; ++j)
          bg[(tap + 1) & 1][j] =
              *(const bf16x8*)(xb + kh1 * 4160 + ((j << 4) + kw1) * 8);
      }
#pragma unroll
      for (int i = 0; i < 4; ++i)
#pragma unroll
        for (int j = 0; j < 4; ++j)
          acc[i][j] = __builtin_amdgcn_mfma_f32_16x16x32_bf16(
              af[tap % 3][i], bg[tap & 1][j], acc[i][j], 0, 0, 0);
    }
    __syncthreads();
  }

  // epilogue: D col = lane&15 (w), row = quad*4+reg (co); y = (acc+bias)*scale
#pragma unroll
  for (int i = 0; i < 4; ++i) {
    const int mrow = m0 + wave_m + (i << 4) + (quad << 2);
    float bs[4], ss[4];
#pragma unroll
    for (int r = 0; r < 4; ++r) {
      bs[r] = bias[mrow + r];
      ss[r] = scale[(b << 8) + mrow + r];
    }
#pragma unroll
    for (int j = 0; j < 4; ++j) {
      const int wcol = wave_n + (j << 4) + n0;
      float* op = out + ((((b << 8) + mrow) * HH) + h) * WW + wcol;
#pragma unroll
      for (int r = 0; r < 4; ++r)
        op[r * (HH * WW)] = (acc[i][j][r] + bs[r]) * ss[r];
    }
  }
}

extern "C" void kernel_launch(void* const* d_in, const int* in_sizes, int n_in,
                              void* d_out, int out_size, void* d_ws, size_t ws_size,
                              hipStream_t stream) {
  const float* x  = (const float*)d_in[0];
  const float* wd = (const float*)d_in[1];
  const float* bd = (const float*)d_in[2];
  const float* w1 = (const float*)d_in[3];
  const float* b1 = (const float*)d_in[4];
  const float* w2 = (const float*)d_in[5];
  const float* b2 = (const float*)d_in[6];
  float* out = (float*)d_out;

  // workspace layout
  char* ws = (char*)d_ws;
  unsigned short* Xc = (unsigned short*)ws;                         // 67108864 B
  unsigned short* Wt = (unsigned short*)(ws + 67108864);            //  1179648 B
  float* sums  = (float*)(ws + 67108864 + 1179648);                 //    40960 B
  float* scale = (float*)(ws + 67108864 + 1179648 + 40960);         //     8192 B

  k_convert_w<<<dim3(32), dim3(256), 0, stream>>>(wd, Wt, sums);
  k_transpose_x<<<dim3(2, 4, 1024), dim3(256), 0, stream>>>(x, Xc, sums);
  k_pool_se<<<dim3(8), dim3(256), 0, stream>>>(x, wd, bd, w1, b1, w2, b2, sums, scale);
  k_conv<<<dim3(2, 512), dim3(256), 0, stream>>>(Xc, Wt, bd, scale, out, 0);
  k_conv<<<dim3(2, 512), dim3(256), 0, stream>>>(Xc, Wt, bd, scale, out, 512);
}

// Round 5
// 414.843 us; speedup vs baseline: 1.3024x; 1.3024x over previous
//
#include <hip/hip_runtime.h>
#include <hip/hip_bf16.h>

#define BB 8
#define CC 256
#define HH 128
#define WW 128

typedef __attribute__((ext_vector_type(8))) short bf16x8;
typedef __attribute__((ext_vector_type(4))) float f32x4;

// fp32 -> bf16 round-to-nearest-even
static __device__ __forceinline__ unsigned short f2bf(float f) {
  unsigned int u = __builtin_bit_cast(unsigned int, f);
  u += 0x7fffu + ((u >> 16) & 1u);
  return (unsigned short)(u >> 16);
}

// async 16B global->LDS; LDS dest = wave-uniform base + lane*16
static __device__ __forceinline__ void async16(const void* g, void* l) {
#if __has_builtin(__builtin_amdgcn_global_load_lds)
  __builtin_amdgcn_global_load_lds(
      (__attribute__((address_space(1))) void*)(unsigned long long)(g),
      (__attribute__((address_space(3))) void*)(unsigned int)(unsigned long long)(l),
      16, 0, 0);
#else
  *(bf16x8*)l = *(const bf16x8*)g;
#endif
}

// ---------------------------------------------------------------------------
// Kernel 1: w_deform [co][ci][3][3] fp32 -> Wt2 [tap][ci_octet][co][8] bf16.
// LDS-tiled, coalesced loads and stores. Also zeroes sums[] (18432 floats).
// ---------------------------------------------------------------------------
__global__ __launch_bounds__(256) void k_convert_w(const float* __restrict__ w,
                                                   unsigned short* __restrict__ Wt,
                                                   float* __restrict__ sums) {
  __shared__ unsigned short lw[8 * 2304];  // [cl][ci][tap] bf16
  const int t = threadIdx.x;
  const int co0 = blockIdx.x << 3;
  for (int z = blockIdx.x * 256 + t; z < 18432; z += 8192) sums[z] = 0.f;
  const float* src = w + co0 * 2304;
  for (int k = t; k < 18432; k += 256) lw[k] = f2bf(src[k]);  // coalesced
  __syncthreads();
  for (int g = t; g < 18432; g += 256) {
    const int tap = g >> 11, rem = g & 2047;
    const int o = rem >> 6, rem2 = rem & 63;
    const int cl = rem2 >> 3, e = rem2 & 7;
    Wt[(((tap << 5) + o) << 11) + ((co0 + cl) << 3) + e] =
        lw[cl * 2304 + ((o << 3) + e) * 9 + tap];
  }
}

// ---------------------------------------------------------------------------
// Kernel 2: x [b][c][h][w] fp32 -> Xc2 [b][h][ci_octet][w][8] bf16,
// fused partial sums for the closed-form SE pool. sums layout (x2048 each):
// [0]=S [1]=R0 [2]=R1 [3]=C0 [4]=C1 [5]=x00 [6]=x0W [7]=xH0 [8]=xHW
// ---------------------------------------------------------------------------
__global__ __launch_bounds__(256) void k_transpose_x(const float* __restrict__ x,
                                                     unsigned short* __restrict__ Xc,
                                                     float* __restrict__ sums) {
  __shared__ float tile[64][65];
  const int t = threadIdx.x;
  const int bz = blockIdx.z;
  const int b = bz >> 7, h = bz & 127;
  const int c0 = blockIdx.y << 6, w0 = blockIdx.x << 6;
  const float* xp = x + (((b * CC) * HH) + h) * WW;
#pragma unroll
  for (int i = 0; i < 4; ++i) {
    int idx = t + (i << 8);
    int cr = idx >> 4, wq = idx & 15;
    float4 v = *(const float4*)(xp + (c0 + cr) * (HH * WW) + w0 + (wq << 2));
    tile[cr][(wq << 2) + 0] = v.x;
    tile[cr][(wq << 2) + 1] = v.y;
    tile[cr][(wq << 2) + 2] = v.z;
    tile[cr][(wq << 2) + 3] = v.w;
  }
  __syncthreads();
  // ---- write out in [octet][w][8] layout ----
  const int ob = c0 >> 3;
#pragma unroll
  for (int i = 0; i < 2; ++i) {
    int g = t + (i << 8);          // 0..511
    int o = g >> 6, wr = g & 63;
    bf16x8 v;
#pragma unroll
    for (int e = 0; e < 8; ++e) v[e] = (short)f2bf(tile[(o << 3) + e][wr]);
    *(bf16x8*)(Xc + ((((b << 7) + h) * 32) + ob + o) * 1024 + (w0 + wr) * 8) = v;
  }
  // ---- fused partial sums (incl. the 4 corners, from LDS) ----
  {
    const int c = t >> 2, seg = t & 3;
    float s = 0.f;
#pragma unroll
    for (int k = 0; k < 16; ++k) s += tile[c][(seg << 4) + k];
    s += __shfl_xor(s, 1);
    s += __shfl_xor(s, 2);
    const int ci = b * CC + c0 + c;
    if (seg == 0) {
      atomicAdd(&sums[ci], s);                       // S
      if (h == 0)   atomicAdd(&sums[2048 + ci], s);  // R0
      if (h == 127) atomicAdd(&sums[4096 + ci], s);  // R1
      if (w0 == 0) {
        atomicAdd(&sums[6144 + ci], tile[c][0]);                   // C0
        if (h == 0)   atomicAdd(&sums[10240 + ci], tile[c][0]);    // x00
        if (h == 127) atomicAdd(&sums[14336 + ci], tile[c][0]);    // xH0
      }
    }
    if (seg == 3 && w0 == 64) {
      atomicAdd(&sums[8192 + ci], tile[c][63]);                    // C1
      if (h == 0)   atomicAdd(&sums[12288 + ci], tile[c][63]);     // x0W
      if (h == 127) atomicAdd(&sums[16384 + ci], tile[c][63]);     // xHW
    }
  }
}

// ---------------------------------------------------------------------------
// Kernel 3a: p[b][co] = bd[co] + (1/16384) * sum_k w[co][k] * ts[b][k].
// 256 blocks (8 b x 32 co-groups of 8): each wave 2 co, lanes split K=2304
// with coalesced float4 reads. (Round-2..4 version ran this on 8 blocks ->
// 117 us latency-bound; this is the parallelism fix.)
// ---------------------------------------------------------------------------
__global__ __launch_bounds__(256) void k_pool2(const float* __restrict__ w,
                                               const float* __restrict__ bd,
                                               const float* __restrict__ sums,
                                               float* __restrict__ p_buf) {
  __shared__ float ts[2304];   // flat [ci*9 + tap]
  const int b = blockIdx.y, t = threadIdx.x;
  const int lane = t & 63, wid = t >> 6;
  {
    const int ci = (b << 8) + t;
    const float S  = sums[ci];
    const float R0 = sums[2048 + ci], R1 = sums[4096 + ci];
    const float C0 = sums[6144 + ci], C1 = sums[8192 + ci];
    const float x00 = sums[10240 + ci], x0W = sums[12288 + ci];
    const float xH0 = sums[14336 + ci], xHW = sums[16384 + ci];
    const float er[3] = {R1, 0.f, R0};
    const float ec[3] = {C1, 0.f, C0};
    const float cor[9] = {xHW, 0.f, xH0, 0.f, 0.f, 0.f, x0W, 0.f, x00};
#pragma unroll
    for (int kh = 0; kh < 3; ++kh)
#pragma unroll
      for (int kw = 0; kw < 3; ++kw)
        ts[t * 9 + kh * 3 + kw] = S - er[kh] - ec[kw] + cor[kh * 3 + kw];
  }
  __syncthreads();
  float4 tv[9];
#pragma unroll
  for (int q = 0; q < 9; ++q) tv[q] = *(const float4*)&ts[(q * 64 + lane) * 4];
  const int co = (blockIdx.x << 3) + (wid << 1);
#pragma unroll
  for (int c2 = 0; c2 < 2; ++c2) {
    const float4* wr = (const float4*)(w + (co + c2) * 2304) + lane;
    float s = 0.f;
#pragma unroll
    for (int q = 0; q < 9; ++q) {
      float4 wv = wr[q * 64];
      s += wv.x * tv[q].x + wv.y * tv[q].y + wv.z * tv[q].z + wv.w * tv[q].w;
    }
    s += __shfl_xor(s, 1);  s += __shfl_xor(s, 2);  s += __shfl_xor(s, 4);
    s += __shfl_xor(s, 8);  s += __shfl_xor(s, 16); s += __shfl_xor(s, 32);
    if (lane == 0) p_buf[(b << 8) + co + c2] = bd[co + c2] + s * (1.0f / 16384.0f);
  }
}

// ---------------------------------------------------------------------------
// Kernel 3b: scale = sigmoid(W2 relu(W1 p + b1) + b2). 8 blocks, all waves.
// ---------------------------------------------------------------------------
__global__ __launch_bounds__(256) void k_se2(const float* __restrict__ p_buf,
                                             const float* __restrict__ w1,
                                             const float* __restrict__ b1,
                                             const float* __restrict__ w2,
                                             const float* __restrict__ b2,
                                             float* __restrict__ scale) {
  __shared__ float p[CC];
  __shared__ float h1[64];
  const int b = blockIdx.x, t = threadIdx.x;
  const int lane = t & 63, wid = t >> 6;
  p[t] = p_buf[(b << 8) + t];
  __syncthreads();
  {
    const float4 pv = *(const float4*)&p[lane << 2];
#pragma unroll
    for (int i = 0; i < 16; ++i) {
      const int r = (wid << 4) + i;
      float4 wv = ((const float4*)(w1 + (r << 8)))[lane];
      float s = wv.x * pv.x + wv.y * pv.y + wv.z * pv.z + wv.w * pv.w;
      s += __shfl_xor(s, 1);  s += __shfl_xor(s, 2);  s += __shfl_xor(s, 4);
      s += __shfl_xor(s, 8);  s += __shfl_xor(s, 16); s += __shfl_xor(s, 32);
      if (lane == 0) {
        float v = b1[r] + s;
        h1[r] = v > 0.f ? v : 0.f;
      }
    }
  }
  __syncthreads();
  {
    float s = b2[t];
    const float* wr = w2 + (t << 6);
#pragma unroll
    for (int k = 0; k < 64; ++k) s += wr[k] * h1[k];
    scale[(b << 8) + t] = 1.0f / (1.0f + expf(-s));
  }
}

// ---------------------------------------------------------------------------
// Kernel 4: implicit-GEMM conv, MFMA bf16. Block = 128 co x one W row.
// A from L2 (Wt2 1.2 MB), B double-buffered in LDS via global_load_lds, one
// barrier per ci-chunk. Epilogue fuses +bias, *scale. Single full-grid launch.
// ---------------------------------------------------------------------------
__global__ __launch_bounds__(256, 3) void k_conv(
    const unsigned short* __restrict__ Xc, const unsigned short* __restrict__ Wt,
    const float* __restrict__ bias, const float* __restrict__ scale,
    float* __restrict__ out) {
  __shared__ __align__(16) unsigned short Xs[2 * 12480];  // [buf][dh:3][oct:4][wp:130][8]
  const int t = threadIdx.x;
  const int lin = (blockIdx.y << 1) | blockIdx.x;
  const int Wk = ((lin & 7) << 8) | (lin >> 3);   // XCD k -> b=k, contiguous h
  const int m0 = (Wk & 1) << 7;
  const int bh = Wk >> 1;
  const int b = bh >> 7, h = bh & 127;
  const int lane = t & 63, wid = t >> 6;
  const int wave_m = (wid & 1) << 6, wave_n = (wid >> 1) << 6;
  const int n0 = lane & 15, quad = lane >> 4;
  const int part = wid & 1, rsel = wid >> 1;

  bf16x8 z8 = {0, 0, 0, 0, 0, 0, 0, 0};
  // zero halo columns wp=0 and wp=129 (both buffers), once
  if (t < 48) {
    int bi = t / 24, rem = t % 24;
    int dh = rem >> 3, rem2 = rem & 7, q = rem2 >> 1, side = rem2 & 1;
    *(bf16x8*)&Xs[bi * 12480 + dh * 4160 + q * 1040 + (side ? 1032 : 0)] = z8;
  }
  // out-of-image rows stay zero (staging skips them)
  if (h == 0 || h == 127) {
    const int dhz = (h == 0) ? 0 : 2;
    for (int g = t; g < 1040; g += 256) {
      int bi = g >= 520, gg = g - bi * 520;
      *(bf16x8*)&Xs[bi * 12480 + dhz * 4160 + gg * 8] = z8;
    }
  }

  auto stage = [&](int cb8, int bi) {
    const int ob = cb8 << 2;
#pragma unroll
    for (int r = 0; r < 6; ++r) {
      const int rr = (r << 1) | rsel;      // 12 regions of 2 KB: (dh, octet)
      const int dh = rr >> 2, q = rr & 3;
      const int hh = h - 1 + dh;
      if (hh >= 0 && hh < HH) {
        const unsigned short* gp =
            Xc + ((((b << 7) + hh) * 32 + ob + q) << 10) + (part << 9) + (lane << 3);
        unsigned short* lp =
            &Xs[bi * 12480 + dh * 4160 + q * 1040 + 8 + (part << 9) + (lane << 3)];
        async16(gp, lp);
      }
    }
  };

  f32x4 acc[4][4];
  f32x4 zero4 = {0.f, 0.f, 0.f, 0.f};
#pragma unroll
  for (int i = 0; i < 4; ++i)
#pragma unroll
    for (int j = 0; j < 4; ++j) acc[i][j] = zero4;

  stage(0, 0);
  __syncthreads();

  for (int cb8 = 0; cb8 < 8; ++cb8) {
    const int cur = cb8 & 1;
    if (cb8 < 7) stage(cb8 + 1, cur ^ 1);
    // A base: Wt2[tap][(cb8*4)+quad][co][8]; B base in current Xs buffer
    const unsigned short* wb =
        Wt + ((((cb8 << 2) + quad) << 8) + m0 + wave_m + n0) * 8;
    const unsigned short* xb = &Xs[cur * 12480 + quad * 1040 + (wave_n + n0) * 8];

    bf16x8 af[3][4], bg[2][4];
#pragma unroll
    for (int i = 0; i < 4; ++i) af[0][i] = *(const bf16x8*)(wb + i * 128);
#pragma unroll
    for (int i = 0; i < 4; ++i) af[1][i] = *(const bf16x8*)(wb + 65536 + i * 128);
#pragma unroll
    for (int j = 0; j < 4; ++j) bg[0][j] = *(const bf16x8*)(xb + (j << 4) * 8);

#pragma unroll
    for (int tap = 0; tap < 9; ++tap) {
      if (tap < 7) {   // A prefetch, 2 taps ahead
#pragma unroll
        for (int i = 0; i < 4; ++i)
          af[(tap + 2) % 3][i] = *(const bf16x8*)(wb + (tap + 2) * 65536 + i * 128);
      }
      if (tap < 8) {   // B prefetch, 1 tap ahead
        const int kh1 = (tap + 1) / 3, kw1 = (tap + 1) % 3;
#pragma unroll
        for (int j = 0; j < 4; ++j)
          bg[(tap + 1) & 1][j] =
              *(const bf16x8*)(xb + kh1 * 4160 + ((j << 4) + kw1) * 8);
      }
#pragma unroll
      for (int i = 0; i < 4; ++i)
#pragma unroll
        for (int j = 0; j < 4; ++j)
          acc[i][j] = __builtin_amdgcn_mfma_f32_16x16x32_bf16(
              af[tap % 3][i], bg[tap & 1][j], acc[i][j], 0, 0, 0);
    }
    __syncthreads();
  }

  // epilogue: D col = lane&15 (w), row = quad*4+reg (co); y = (acc+bias)*scale
#pragma unroll
  for (int i = 0; i < 4; ++i) {
    const int mrow = m0 + wave_m + (i << 4) + (quad << 2);
    float bs[4], ss[4];
#pragma unroll
    for (int r = 0; r < 4; ++r) {
      bs[r] = bias[mrow + r];
      ss[r] = scale[(b << 8) + mrow + r];
    }
#pragma unroll
    for (int j = 0; j < 4; ++j) {
      const int wcol = wave_n + (j << 4) + n0;
      float* op = out + ((((b << 8) + mrow) * HH) + h) * WW + wcol;
#pragma unroll
      for (int r = 0; r < 4; ++r)
        op[r * (HH * WW)] = (acc[i][j][r] + bs[r]) * ss[r];
    }
  }
}

extern "C" void kernel_launch(void* const* d_in, const int* in_sizes, int n_in,
                              void* d_out, int out_size, void* d_ws, size_t ws_size,
                              hipStream_t stream) {
  const float* x  = (const float*)d_in[0];
  const float* wd = (const float*)d_in[1];
  const float* bd = (const float*)d_in[2];
  const float* w1 = (const float*)d_in[3];
  const float* b1 = (const float*)d_in[4];
  const float* w2 = (const float*)d_in[5];
  const float* b2 = (const float*)d_in[6];
  float* out = (float*)d_out;

  // workspace layout
  char* ws = (char*)d_ws;
  unsigned short* Xc = (unsigned short*)ws;                     // 67108864 B
  unsigned short* Wt = (unsigned short*)(ws + 67108864);        //  1179648 B
  float* sums  = (float*)(ws + 68288512);                       //    73728 B
  float* p_buf = (float*)(ws + 68362240);                       //     8192 B
  float* scale = (float*)(ws + 68370432);                       //     8192 B

  k_convert_w<<<dim3(32), dim3(256), 0, stream>>>(wd, Wt, sums);
  k_transpose_x<<<dim3(2, 4, 1024), dim3(256), 0, stream>>>(x, Xc, sums);
  k_pool2<<<dim3(32, 8), dim3(256), 0, stream>>>(wd, bd, sums, p_buf);
  k_se2<<<dim3(8), dim3(256), 0, stream>>>(p_buf, w1, b1, w2, b2, scale);
  k_conv<<<dim3(2, 1024), dim3(256), 0, stream>>>(Xc, Wt, bd, scale, out);
}